// Round 1
// baseline (704.186 us; speedup 1.0000x reference)
//
#include <hip/hip_runtime.h>
#include <hip/hip_bf16.h>
#include <math.h>

// ---------------- problem constants ----------------
#define OC     256
#define IC     128
#define HW     56
#define NB     64
#define KK     1152          // IC*9
#define HP     58            // padded spatial
#define PIX    (HW*HW)       // 3136
#define XPAD_ELEMS ((long)NB*HP*HP*IC)   // 27,557,888
#define A_ELEMS    (OC*KK)               // 294,912

typedef __attribute__((ext_vector_type(8))) short          bf16x8;
typedef __attribute__((ext_vector_type(8))) unsigned short u16x8;
typedef __attribute__((ext_vector_type(4))) float          f32x4;

__device__ __forceinline__ void async_load16(const void* g, void* l) {
    __builtin_amdgcn_global_load_lds(
        (const __attribute__((address_space(1))) void*)g,
        (__attribute__((address_space(3))) void*)l, 16, 0, 0);
}

// bf16 RNE convert
__device__ __forceinline__ unsigned short f2bf(float f) {
    unsigned int u = __float_as_uint(f);
    return (unsigned short)((u + 0x7fffu + ((u >> 16) & 1u)) >> 16);
}
__device__ __forceinline__ float bf2f(unsigned short b) {
    return __uint_as_float(((unsigned int)b) << 16);
}

// XOR-swizzled LDS element offset (2-way bank aliasing only — free, m136)
__device__ __forceinline__ int lds_off(int row, int q) {
    return row * 32 + (((q ^ (row >> 1)) & 3) << 3);
}

// ---------------- kernel 1: weights + BN constants ----------------
__global__ __launch_bounds__(256) void prep_weights(
        const float* __restrict__ phase, const float* __restrict__ gamma,
        const float* __restrict__ beta,  const float* __restrict__ rmean,
        const float* __restrict__ rvar,
        __hip_bfloat16* __restrict__ ah, __hip_bfloat16* __restrict__ al,
        float* __restrict__ scale, float* __restrict__ bias) {
    int g = blockIdx.x * 256 + threadIdx.x;      // 0 .. 294911
    int oc = g / KK;
    int kk = g - oc * KK;
    int kpos = kk >> 7;          // kh*3+kw
    int ic   = kk & 127;
    int j    = ic * 9 + kpos;    // original flat k = ic*9 + kh*3 + kw
    int pidx = (((oc >> 3) * 144 + (j >> 3)) * 8 + (oc & 7)) * 8 + (j & 7);
    double phi = (double)phase[pidx];
    double c   = cos(phi);
    const double a = 0.987, r = 0.99;
    double num = a*a - 2.0*a*r*c + r*r;
    double den = 1.0 - 2.0*a*r*c + (a*r)*(a*r);
    float t = (float)(num / den);
    unsigned short hb = f2bf(t);
    float hf = bf2f(hb);
    ((unsigned short*)ah)[g] = hb;
    ((unsigned short*)al)[g] = f2bf(t - hf);
    if (g < OC) {
        float inv = gamma[g] / sqrtf(rvar[g] + 1e-5f);
        scale[g] = inv;
        bias[g]  = beta[g] - rmean[g] * inv;
    }
}

// ---------------- kernel 2: pad + transpose + bf16 hi/lo split ----------------
__global__ __launch_bounds__(256) void prep_x(
        const float* __restrict__ x,
        __hip_bfloat16* __restrict__ xh, __hip_bfloat16* __restrict__ xl) {
    int hp  = blockIdx.x;    // 0..57
    int img = blockIdx.y;    // 0..63
    __shared__ float tile[IC * 57];   // [ic][w], stride 57
    int t = threadIdx.x;
    bool border = (hp == 0) || (hp == HP - 1);
    if (!border) {
        int h = hp - 1;
        const float* src = x + (long)img * IC * PIX + h * HW;
#pragma unroll
        for (int i = 0; i < 7; ++i) {            // 128*14 float4 = 1792
            int idx = i * 256 + t;
            int ic  = idx / 14;
            int w4  = (idx - ic * 14) * 4;
            float4 v = *(const float4*)&src[(long)ic * PIX + w4];
            tile[ic * 57 + w4 + 0] = v.x;
            tile[ic * 57 + w4 + 1] = v.y;
            tile[ic * 57 + w4 + 2] = v.z;
            tile[ic * 57 + w4 + 3] = v.w;
        }
    }
    __syncthreads();
    long base = ((long)(img * HP + hp)) * HP * IC;
#pragma unroll
    for (int i = 0; i < 4; ++i) {                // 58*16 = 928 vec-tasks
        int v = i * 256 + t;
        if (v < 928) {
            int icg = v & 15;                    // 8 ic per task
            int wp  = v >> 4;                    // 0..57
            bool inw = !border && wp >= 1 && wp <= HW;
            u16x8 hv, lv;
#pragma unroll
            for (int j = 0; j < 8; ++j) {
                float f = inw ? tile[(icg * 8 + j) * 57 + (wp - 1)] : 0.f;
                unsigned short hb = f2bf(f);
                hv[j] = hb;
                lv[j] = f2bf(f - bf2f(hb));
            }
            long o = base + wp * IC + icg * 8;
            *(u16x8*)&((unsigned short*)xh)[o] = hv;
            *(u16x8*)&((unsigned short*)xl)[o] = lv;
        }
    }
}

// ---------------- kernel 3: implicit GEMM conv + BN + ReLU6 ----------------
// Restructure vs previous version:
//  - block tile 256 pix x 128 oc, 4 waves, per-wave tile 128x64 (8x4 frags):
//    LDS-read cyc per MFMA-FLOP drops 25% (was the binding resource at 45% MfmaUtil).
//  - ring-3 LDS (3 x 48 KB = 144 KB) + counted s_waitcnt vmcnt(12) + raw s_barrier:
//    staging for chunk c+2 stays in flight across barriers (never vmcnt(0) in loop).
//  - register fragment double-buffer: READF(c+1) overlaps MFMAS(c).
// Slot-safety invariant: reads of slot s (chunk c-1) drain at MFMAS(c-1) before
// barrier-2 of body c-1; the overwrite of s is ISSUE in body c. Two s_barrier per
// chunk; sched_barrier(0) after each to pin ds_read/DMA ordering.
__global__ __launch_bounds__(256, 1) void conv_gemm(
        const __hip_bfloat16* __restrict__ ah, const __hip_bfloat16* __restrict__ al,
        const __hip_bfloat16* __restrict__ xh, const __hip_bfloat16* __restrict__ xl,
        const float* __restrict__ scale, const float* __restrict__ bias,
        float* __restrict__ out) {
    __shared__ __hip_bfloat16 sXh[3][8192];   // 256 pix rows x 32 k
    __shared__ __hip_bfloat16 sXl[3][8192];
    __shared__ __hip_bfloat16 sWh[3][4096];   // 128 oc rows x 32 k
    __shared__ __hip_bfloat16 sWl[3][4096];   // total 144 KB

    // XCD-aware swizzle: XCD x owns imgs [x*8, x*8+8); 26 consecutive blocks
    // per img keep its 3.4 MB x-slab L2-resident.
    int b   = blockIdx.x;
    int xcd = b & 7;
    int idx = b >> 3;              // 0..207 per XCD
    int img = xcd * 8 + idx / 26;
    int rem = idx % 26;
    int mt  = rem >> 1;            // 0..12  pixel tile (256 rows)
    int ot  = rem & 1;             // oc tile (128)

    int t    = threadIdx.x;
    int lane = t & 63;
    int wave = t >> 6;
    int ww   = wave & 1;           // oc half (64)
    int wx   = wave >> 1;          // pix half (128)

    int row0 = t >> 2;
    int col0 = (((t & 3) ^ ((t >> 3) & 3))) << 3;   // pre-swizzled global col

    const __hip_bfloat16* pwh0 = ah + (long)(ot * 128 + row0) * KK + col0;
    const __hip_bfloat16* pwh1 = pwh0 + (long)64 * KK;

    int mb = mt * 256 + row0;
    int m0 = mb;        if (m0 > PIX - 1) m0 = PIX - 1;
    int m1 = mb + 64;   if (m1 > PIX - 1) m1 = PIX - 1;
    int m2 = mb + 128;  if (m2 > PIX - 1) m2 = PIX - 1;
    int m3 = mb + 192;  if (m3 > PIX - 1) m3 = PIX - 1;
    int h0 = m0 / HW, w0 = m0 - h0 * HW;
    int h1 = m1 / HW, w1 = m1 - h1 * HW;
    int h2 = m2 / HW, w2 = m2 - h2 * HW;
    int h3 = m3 / HW, w3 = m3 - h3 * HW;
    const __hip_bfloat16* pxh0 = xh + (long)((img * HP + h0) * HP + w0) * IC + col0;
    const __hip_bfloat16* pxh1 = xh + (long)((img * HP + h1) * HP + w1) * IC + col0;
    const __hip_bfloat16* pxh2 = xh + (long)((img * HP + h2) * HP + w2) * IC + col0;
    const __hip_bfloat16* pxh3 = xh + (long)((img * HP + h3) * HP + w3) * IC + col0;

    int wr[4], xr[8];
#pragma unroll
    for (int f = 0; f < 4; ++f)
        wr[f] = lds_off(ww * 64 + f * 16 + (lane & 15), lane >> 4);
#pragma unroll
    for (int f = 0; f < 8; ++f)
        xr[f] = lds_off(wx * 128 + f * 16 + (lane & 15), lane >> 4);

    f32x4 acc[4][8];
#pragma unroll
    for (int i = 0; i < 4; ++i)
#pragma unroll
        for (int j = 0; j < 8; ++j) acc[i][j] = (f32x4){0.f, 0.f, 0.f, 0.f};

    bf16x8 wH0[4], wL0[4], xH0[8], xL0[8];
    bf16x8 wH1[4], wL1[4], xH1[8], xL1[8];

// stage chunk k into ring slot S: 12 global_load_lds x 256 thr x 16 B = 48 KB
#define ISSUE(k, S)                                                            \
    {                                                                          \
        int _k = (k);                                                          \
        int bs = 32 * _k + (_k >= 12 ? 7040 : 0) + (_k >= 24 ? 7040 : 0);      \
        long ao = (long)_k * 32;                                               \
        async_load16(pwh0 + ao,              &sWh[S][t * 8]);                  \
        async_load16(pwh1 + ao,              &sWh[S][2048 + t * 8]);           \
        async_load16(pwh0 + A_ELEMS + ao,    &sWl[S][t * 8]);                  \
        async_load16(pwh1 + A_ELEMS + ao,    &sWl[S][2048 + t * 8]);           \
        async_load16(pxh0 + bs,              &sXh[S][t * 8]);                  \
        async_load16(pxh1 + bs,              &sXh[S][2048 + t * 8]);           \
        async_load16(pxh2 + bs,              &sXh[S][4096 + t * 8]);           \
        async_load16(pxh3 + bs,              &sXh[S][6144 + t * 8]);           \
        async_load16(pxh0 + XPAD_ELEMS + bs, &sXl[S][t * 8]);                  \
        async_load16(pxh1 + XPAD_ELEMS + bs, &sXl[S][2048 + t * 8]);           \
        async_load16(pxh2 + XPAD_ELEMS + bs, &sXl[S][4096 + t * 8]);           \
        async_load16(pxh3 + XPAD_ELEMS + bs, &sXl[S][6144 + t * 8]);           \
    }

#define READF(WH, WL, XH, XL, S)                                               \
    {                                                                          \
        _Pragma("unroll")                                                      \
        for (int f = 0; f < 4; ++f) {                                          \
            WH[f] = *(const bf16x8*)&sWh[S][wr[f]];                            \
            WL[f] = *(const bf16x8*)&sWl[S][wr[f]];                            \
        }                                                                      \
        _Pragma("unroll")                                                      \
        for (int f = 0; f < 8; ++f) {                                          \
            XH[f] = *(const bf16x8*)&sXh[S][xr[f]];                            \
            XL[f] = *(const bf16x8*)&sXl[S][xr[f]];                            \
        }                                                                      \
    }

#define MFMAS(WH, WL, XH, XL)                                                  \
    {                                                                          \
        _Pragma("unroll")                                                      \
        for (int fw = 0; fw < 4; ++fw)                                         \
            _Pragma("unroll")                                                  \
            for (int fx = 0; fx < 8; ++fx) {                                   \
                acc[fw][fx] = __builtin_amdgcn_mfma_f32_16x16x32_bf16(WL[fw], XH[fx], acc[fw][fx], 0, 0, 0); \
                acc[fw][fx] = __builtin_amdgcn_mfma_f32_16x16x32_bf16(WH[fw], XL[fx], acc[fw][fx], 0, 0, 0); \
                acc[fw][fx] = __builtin_amdgcn_mfma_f32_16x16x32_bf16(WH[fw], XH[fx], acc[fw][fx], 0, 0, 0); \
            }                                                                  \
    }

// chunk k body: stage(k+2); wait stage(k+1) landed (12 newest = stage(k+2));
// barrier; read frags(k+1); MFMA frags(k); barrier.
#define BODY(k, SNXT, SSTG, WHc, WLc, XHc, XLc, WHn, WLn, XHn, XLn)            \
    ISSUE((k) + 2, SSTG);                                                      \
    asm volatile("s_waitcnt vmcnt(12)" ::: "memory");                          \
    __builtin_amdgcn_s_barrier();                                              \
    __builtin_amdgcn_sched_barrier(0);                                         \
    READF(WHn, WLn, XHn, XLn, SNXT);                                           \
    MFMAS(WHc, WLc, XHc, XLc);                                                 \
    __builtin_amdgcn_s_barrier();                                              \
    __builtin_amdgcn_sched_barrier(0);

    // prologue: stage chunks 0,1; wait chunk 0; read frags(0)
    ISSUE(0, 0);
    ISSUE(1, 1);
    asm volatile("s_waitcnt vmcnt(12)" ::: "memory");
    __builtin_amdgcn_s_barrier();
    __builtin_amdgcn_sched_barrier(0);
    READF(wH0, wL0, xH0, xL0, 0);

#pragma unroll 1
    for (int it = 0; it < 5; ++it) {          // chunks 0..29
        int kb = it * 6;
        BODY(kb + 0, 1, 2, wH0, wL0, xH0, xL0, wH1, wL1, xH1, xL1);
        BODY(kb + 1, 2, 0, wH1, wL1, xH1, xL1, wH0, wL0, xH0, xL0);
        BODY(kb + 2, 0, 1, wH0, wL0, xH0, xL0, wH1, wL1, xH1, xL1);
        BODY(kb + 3, 1, 2, wH1, wL1, xH1, xL1, wH0, wL0, xH0, xL0);
        BODY(kb + 4, 2, 0, wH0, wL0, xH0, xL0, wH1, wL1, xH1, xL1);
        BODY(kb + 5, 0, 1, wH1, wL1, xH1, xL1, wH0, wL0, xH0, xL0);
    }
    // chunks 30..33 (stages 32..35)
    BODY(30, 1, 2, wH0, wL0, xH0, xL0, wH1, wL1, xH1, xL1);
    BODY(31, 2, 0, wH1, wL1, xH1, xL1, wH0, wL0, xH0, xL0);
    BODY(32, 0, 1, wH0, wL0, xH0, xL0, wH1, wL1, xH1, xL1);
    BODY(33, 1, 2, wH1, wL1, xH1, xL1, wH0, wL0, xH0, xL0);
    // chunk 34: no staging left; drain stage(35); read frags(35) from slot 2
    asm volatile("s_waitcnt vmcnt(0)" ::: "memory");
    __builtin_amdgcn_s_barrier();
    __builtin_amdgcn_sched_barrier(0);
    READF(wH1, wL1, xH1, xL1, 2);
    MFMAS(wH0, wL0, xH0, xL0);
    // chunk 35
    MFMAS(wH1, wL1, xH1, xL1);

#undef ISSUE
#undef READF
#undef MFMAS
#undef BODY

    // epilogue: BN (eval) + ReLU6, store fp32
    int pixc = mt * 256 + wx * 128 + (lane & 15);
    int occ0 = ot * 128 + ww * 64 + ((lane >> 4) << 2);
#pragma unroll
    for (int fw = 0; fw < 4; ++fw) {
#pragma unroll
        for (int r = 0; r < 4; ++r) {
            int oc = occ0 + fw * 16 + r;
            float sc = scale[oc], bi = bias[oc];
            long obase = ((long)(img * OC + oc)) * PIX;
#pragma unroll
            for (int fx = 0; fx < 8; ++fx) {
                int pix = pixc + fx * 16;
                if (pix < PIX) {
                    float v = acc[fw][fx][r] * sc + bi;
                    v = fminf(fmaxf(v, 0.f), 6.f);
                    out[obase + pix] = v;
                }
            }
        }
    }
}

// ---------------- launch ----------------
extern "C" void kernel_launch(void* const* d_in, const int* in_sizes, int n_in,
                              void* d_out, int out_size, void* d_ws, size_t ws_size,
                              hipStream_t stream) {
    const float* x     = (const float*)d_in[0];
    const float* phase = (const float*)d_in[1];
    const float* gamma = (const float*)d_in[2];
    const float* beta  = (const float*)d_in[3];
    const float* rmean = (const float*)d_in[4];
    const float* rvar  = (const float*)d_in[5];
    float* out = (float*)d_out;

    __hip_bfloat16* xh = (__hip_bfloat16*)d_ws;
    __hip_bfloat16* xl = xh + XPAD_ELEMS;
    __hip_bfloat16* ah = xl + XPAD_ELEMS;
    __hip_bfloat16* al = ah + A_ELEMS;
    float* scale = (float*)(al + A_ELEMS);
    float* bias  = scale + OC;

    prep_weights<<<A_ELEMS / 256, 256, 0, stream>>>(phase, gamma, beta, rmean, rvar,
                                                    ah, al, scale, bias);
    prep_x<<<dim3(HP, NB), 256, 0, stream>>>(x, xh, xl);
    conv_gemm<<<NB * 26, 256, 0, stream>>>(ah, al, xh, xl, scale, bias, out);
}

// Round 2
// 588.139 us; speedup vs baseline: 1.1973x; 1.1973x over previous
//
#include <hip/hip_runtime.h>
#include <hip/hip_bf16.h>
#include <math.h>

// ---------------- problem constants ----------------
#define OC     256
#define IC     128
#define HW     56
#define NB     64
#define KK     1152          // IC*9
#define HP     58            // padded spatial
#define PIX    (HW*HW)       // 3136
#define XPAD_ELEMS ((long)NB*HP*HP*IC)   // 27,557,888
#define A_ELEMS    (OC*KK)               // 294,912

typedef __attribute__((ext_vector_type(8))) short          bf16x8;
typedef __attribute__((ext_vector_type(8))) unsigned short u16x8;
typedef __attribute__((ext_vector_type(4))) float          f32x4;

__device__ __forceinline__ void async_load16(const void* g, void* l) {
    __builtin_amdgcn_global_load_lds(
        (const __attribute__((address_space(1))) void*)g,
        (__attribute__((address_space(3))) void*)l, 16, 0, 0);
}

// bf16 RNE convert
__device__ __forceinline__ unsigned short f2bf(float f) {
    unsigned int u = __float_as_uint(f);
    return (unsigned short)((u + 0x7fffu + ((u >> 16) & 1u)) >> 16);
}
__device__ __forceinline__ float bf2f(unsigned short b) {
    return __uint_as_float(((unsigned int)b) << 16);
}

// XOR-swizzled LDS element offset (2-way bank aliasing only — free, m136)
__device__ __forceinline__ int lds_off(int row, int q) {
    return row * 32 + (((q ^ (row >> 1)) & 3) << 3);
}

// ---------------- kernel 1: weights + BN constants ----------------
__global__ __launch_bounds__(256) void prep_weights(
        const float* __restrict__ phase, const float* __restrict__ gamma,
        const float* __restrict__ beta,  const float* __restrict__ rmean,
        const float* __restrict__ rvar,
        __hip_bfloat16* __restrict__ ah, __hip_bfloat16* __restrict__ al,
        float* __restrict__ scale, float* __restrict__ bias) {
    int g = blockIdx.x * 256 + threadIdx.x;      // 0 .. 294911
    int oc = g / KK;
    int kk = g - oc * KK;
    int kpos = kk >> 7;          // kh*3+kw
    int ic   = kk & 127;
    int j    = ic * 9 + kpos;    // original flat k = ic*9 + kh*3 + kw
    int pidx = (((oc >> 3) * 144 + (j >> 3)) * 8 + (oc & 7)) * 8 + (j & 7);
    double phi = (double)phase[pidx];
    double c   = cos(phi);
    const double a = 0.987, r = 0.99;
    double num = a*a - 2.0*a*r*c + r*r;
    double den = 1.0 - 2.0*a*r*c + (a*r)*(a*r);
    float t = (float)(num / den);
    unsigned short hb = f2bf(t);
    float hf = bf2f(hb);
    ((unsigned short*)ah)[g] = hb;
    ((unsigned short*)al)[g] = f2bf(t - hf);
    if (g < OC) {
        float inv = gamma[g] / sqrtf(rvar[g] + 1e-5f);
        scale[g] = inv;
        bias[g]  = beta[g] - rmean[g] * inv;
    }
}

// ---------------- kernel 2: pad + transpose + bf16 hi/lo split ----------------
__global__ __launch_bounds__(256) void prep_x(
        const float* __restrict__ x,
        __hip_bfloat16* __restrict__ xh, __hip_bfloat16* __restrict__ xl) {
    int hp  = blockIdx.x;    // 0..57
    int img = blockIdx.y;    // 0..63
    __shared__ float tile[IC * 57];   // [ic][w], stride 57
    int t = threadIdx.x;
    bool border = (hp == 0) || (hp == HP - 1);
    if (!border) {
        int h = hp - 1;
        const float* src = x + (long)img * IC * PIX + h * HW;
#pragma unroll
        for (int i = 0; i < 7; ++i) {            // 128*14 float4 = 1792
            int idx = i * 256 + t;
            int ic  = idx / 14;
            int w4  = (idx - ic * 14) * 4;
            float4 v = *(const float4*)&src[(long)ic * PIX + w4];
            tile[ic * 57 + w4 + 0] = v.x;
            tile[ic * 57 + w4 + 1] = v.y;
            tile[ic * 57 + w4 + 2] = v.z;
            tile[ic * 57 + w4 + 3] = v.w;
        }
    }
    __syncthreads();
    long base = ((long)(img * HP + hp)) * HP * IC;
#pragma unroll
    for (int i = 0; i < 4; ++i) {                // 58*16 = 928 vec-tasks
        int v = i * 256 + t;
        if (v < 928) {
            int icg = v & 15;                    // 8 ic per task
            int wp  = v >> 4;                    // 0..57
            bool inw = !border && wp >= 1 && wp <= HW;
            u16x8 hv, lv;
#pragma unroll
            for (int j = 0; j < 8; ++j) {
                float f = inw ? tile[(icg * 8 + j) * 57 + (wp - 1)] : 0.f;
                unsigned short hb = f2bf(f);
                hv[j] = hb;
                lv[j] = f2bf(f - bf2f(hb));
            }
            long o = base + wp * IC + icg * 8;
            *(u16x8*)&((unsigned short*)xh)[o] = hv;
            *(u16x8*)&((unsigned short*)xl)[o] = lv;
        }
    }
}

// ---------------- kernel 3: implicit GEMM conv + BN + ReLU6 ----------------
// R0 geometry (128x128 tile, 4 waves, 64KB LDS ring-2, 2 blocks/CU) with the
// loop restructured to counted-vmcnt pipelining:
//  - ISSUE(k+2) into slot k&1, then s_waitcnt vmcnt(8): the 8 just-issued DMAs
//    stay in flight across the barrier; we only wait for chunk k+1's staging
//    (issued one full body earlier -> latency fully hidden).
//  - raw s_barrier + sched_barrier(0) (no __syncthreads vmcnt(0) drain).
//  - explicit lgkmcnt(0) before barrier-2: READF(k+1)'s ds_reads retire before
//    any wave's ISSUE(k+3) overwrites that slot next body (ring-2 reuse hazard).
__global__ __launch_bounds__(256, 2) void conv_gemm(
        const __hip_bfloat16* __restrict__ ah, const __hip_bfloat16* __restrict__ al,
        const __hip_bfloat16* __restrict__ xh, const __hip_bfloat16* __restrict__ xl,
        const float* __restrict__ scale, const float* __restrict__ bias,
        float* __restrict__ out) {
    __shared__ __hip_bfloat16 sAh0[4096], sAl0[4096], sBh0[4096], sBl0[4096];
    __shared__ __hip_bfloat16 sAh1[4096], sAl1[4096], sBh1[4096], sBl1[4096];

    // XCD-aware swizzle: consecutive blockIdx -> XCD round-robin (b&7).
    int b   = blockIdx.x;
    int xcd = b & 7;
    int idx = b >> 3;            // 0..399 per XCD
    int img = xcd * 8 + idx / 50;
    int rem = idx % 50;
    int mt  = rem >> 1;          // 0..24  pixel tile
    int ot  = rem & 1;           // oc tile

    int t    = threadIdx.x;
    int lane = t & 63;
    int wave = t >> 6;
    int wm   = wave & 1;     // oc half (64)
    int wn   = wave >> 1;    // pixel half (64)

    int row0 = t >> 2;
    int col0 = (((t & 3) ^ ((t >> 3) & 3))) << 3;

    const __hip_bfloat16* pah0 = ah + (long)(ot * 128 + row0) * KK + col0;
    const __hip_bfloat16* pah1 = pah0 + (long)64 * KK;
    const __hip_bfloat16* pal0 = al + (long)(ot * 128 + row0) * KK + col0;
    const __hip_bfloat16* pal1 = pal0 + (long)64 * KK;

    int m0 = mt * 128 + row0;      if (m0 > PIX - 1) m0 = PIX - 1;
    int m1 = mt * 128 + row0 + 64; if (m1 > PIX - 1) m1 = PIX - 1;
    int h0 = m0 / HW, w0 = m0 - h0 * HW;
    int h1 = m1 / HW, w1 = m1 - h1 * HW;
    const __hip_bfloat16* pxh0 = xh + (long)((img * HP + h0) * HP + w0) * IC + col0;
    const __hip_bfloat16* pxh1 = xh + (long)((img * HP + h1) * HP + w1) * IC + col0;
    const __hip_bfloat16* pxl0 = xl + (long)((img * HP + h0) * HP + w0) * IC + col0;
    const __hip_bfloat16* pxl1 = xl + (long)((img * HP + h1) * HP + w1) * IC + col0;

    int ar[4], br[4];
#pragma unroll
    for (int f = 0; f < 4; ++f) {
        ar[f] = lds_off(wm * 64 + f * 16 + (lane & 15), lane >> 4);
        br[f] = lds_off(wn * 64 + f * 16 + (lane & 15), lane >> 4);
    }

    f32x4 acc[4][4];
#pragma unroll
    for (int i = 0; i < 4; ++i)
#pragma unroll
        for (int jj = 0; jj < 4; ++jj) acc[i][jj] = (f32x4){0.f, 0.f, 0.f, 0.f};

    bf16x8 aH0[4], aL0[4], bH0[4], bL0[4];
    bf16x8 aH1[4], aL1[4], bH1[4], bL1[4];

#define ISSUE(ci, SAH, SAL, SBH, SBL)                                          \
    {                                                                           \
        int bs = 32 * (ci) + ((ci) >= 12 ? 7040 : 0) + ((ci) >= 24 ? 7040 : 0); \
        long a0 = (long)(ci) * 32;                                              \
        async_load16(pah0 + a0, &SAH[t * 8]);                                   \
        async_load16(pah1 + a0, &SAH[2048 + t * 8]);                            \
        async_load16(pal0 + a0, &SAL[t * 8]);                                   \
        async_load16(pal1 + a0, &SAL[2048 + t * 8]);                            \
        async_load16(pxh0 + bs, &SBH[t * 8]);                                   \
        async_load16(pxh1 + bs, &SBH[2048 + t * 8]);                            \
        async_load16(pxl0 + bs, &SBL[t * 8]);                                   \
        async_load16(pxl1 + bs, &SBL[2048 + t * 8]);                            \
    }

#define READF(AH, AL, BH, BL, SAH, SAL, SBH, SBL)                               \
    {                                                                           \
        _Pragma("unroll")                                                       \
        for (int f = 0; f < 4; ++f) {                                           \
            AH[f] = *(const bf16x8*)&SAH[ar[f]];                                \
            AL[f] = *(const bf16x8*)&SAL[ar[f]];                                \
            BH[f] = *(const bf16x8*)&SBH[br[f]];                                \
            BL[f] = *(const bf16x8*)&SBL[br[f]];                                \
        }                                                                       \
    }

#define MFMAS(AH, AL, BH, BL)                                                   \
    {                                                                           \
        _Pragma("unroll")                                                       \
        for (int fm = 0; fm < 4; ++fm)                                          \
            _Pragma("unroll")                                                   \
            for (int fn = 0; fn < 4; ++fn) {                                    \
                acc[fm][fn] = __builtin_amdgcn_mfma_f32_16x16x32_bf16(AL[fm], BH[fn], acc[fm][fn], 0, 0, 0); \
                acc[fm][fn] = __builtin_amdgcn_mfma_f32_16x16x32_bf16(AH[fm], BL[fn], acc[fm][fn], 0, 0, 0); \
                acc[fm][fn] = __builtin_amdgcn_mfma_f32_16x16x32_bf16(AH[fm], BH[fn], acc[fm][fn], 0, 0, 0); \
            }                                                                   \
    }

// body k: stage(k+2) into slot k&1; wait stage(k+1) landed (8 newest in
// flight = stage(k+2)); barrier; read frags(k+1); MFMA frags(k); lgkm-drain
// the frag reads (slot k+1&1 is overwritten one barrier later); barrier.
#define BODY(k, SAs, SLs, SBs, SBLs, AHn, ALn, BHn, BLn, SAn, SLn, SBn, SBLn,  \
             AHc, ALc, BHc, BLc)                                                \
    ISSUE((k) + 2, SAs, SLs, SBs, SBLs);                                        \
    asm volatile("s_waitcnt vmcnt(8)" ::: "memory");                            \
    __builtin_amdgcn_s_barrier();                                               \
    __builtin_amdgcn_sched_barrier(0);                                          \
    READF(AHn, ALn, BHn, BLn, SAn, SLn, SBn, SBLn);                             \
    MFMAS(AHc, ALc, BHc, BLc);                                                  \
    asm volatile("s_waitcnt lgkmcnt(0)" ::: "memory");                          \
    __builtin_amdgcn_sched_barrier(0);                                          \
    __builtin_amdgcn_s_barrier();                                               \
    __builtin_amdgcn_sched_barrier(0);

    // prologue: stage chunks 0,1; wait chunk 0; read frags(0); fence slot 0
    ISSUE(0, sAh0, sAl0, sBh0, sBl0);
    ISSUE(1, sAh1, sAl1, sBh1, sBl1);
    asm volatile("s_waitcnt vmcnt(8)" ::: "memory");
    __builtin_amdgcn_s_barrier();
    __builtin_amdgcn_sched_barrier(0);
    READF(aH0, aL0, bH0, bL0, sAh0, sAl0, sBh0, sBl0);
    asm volatile("s_waitcnt lgkmcnt(0)" ::: "memory");
    __builtin_amdgcn_sched_barrier(0);
    __builtin_amdgcn_s_barrier();
    __builtin_amdgcn_sched_barrier(0);

#pragma unroll 1
    for (int it = 0; it < 17; ++it) {        // bodies k = 0..33
        BODY(2*it,     sAh0, sAl0, sBh0, sBl0,
                       aH1, aL1, bH1, bL1, sAh1, sAl1, sBh1, sBl1,
                       aH0, aL0, bH0, bL0);
        BODY(2*it + 1, sAh1, sAl1, sBh1, sBl1,
                       aH0, aL0, bH0, bL0, sAh0, sAl0, sBh0, sBl0,
                       aH1, aL1, bH1, bL1);
    }
    // tail: chunk 34 (frags in set0), chunk 35 (staged into slot 1 by body 33)
    asm volatile("s_waitcnt vmcnt(0)" ::: "memory");
    __builtin_amdgcn_s_barrier();
    __builtin_amdgcn_sched_barrier(0);
    READF(aH1, aL1, bH1, bL1, sAh1, sAl1, sBh1, sBl1);
    MFMAS(aH0, aL0, bH0, bL0);               // chunk 34
    MFMAS(aH1, aL1, bH1, bL1);               // chunk 35
#undef ISSUE
#undef READF
#undef MFMAS
#undef BODY

    // epilogue: BN (eval) + ReLU6, store fp32
    int pixc = mt * 128 + wn * 64 + (lane & 15);
    int occ0 = ot * 128 + wm * 64 + ((lane >> 4) << 2);
#pragma unroll
    for (int fm = 0; fm < 4; ++fm) {
#pragma unroll
        for (int r = 0; r < 4; ++r) {
            int oc = occ0 + fm * 16 + r;
            float sc = scale[oc], bi = bias[oc];
            long obase = ((long)(img * OC + oc)) * PIX;
#pragma unroll
            for (int fn = 0; fn < 4; ++fn) {
                int pix = pixc + fn * 16;
                if (pix < PIX) {
                    float v = acc[fm][fn][r] * sc + bi;
                    v = fminf(fmaxf(v, 0.f), 6.f);
                    out[obase + pix] = v;
                }
            }
        }
    }
}

// ---------------- launch ----------------
extern "C" void kernel_launch(void* const* d_in, const int* in_sizes, int n_in,
                              void* d_out, int out_size, void* d_ws, size_t ws_size,
                              hipStream_t stream) {
    const float* x     = (const float*)d_in[0];
    const float* phase = (const float*)d_in[1];
    const float* gamma = (const float*)d_in[2];
    const float* beta  = (const float*)d_in[3];
    const float* rmean = (const float*)d_in[4];
    const float* rvar  = (const float*)d_in[5];
    float* out = (float*)d_out;

    __hip_bfloat16* xh = (__hip_bfloat16*)d_ws;
    __hip_bfloat16* xl = xh + XPAD_ELEMS;
    __hip_bfloat16* ah = xl + XPAD_ELEMS;
    __hip_bfloat16* al = ah + A_ELEMS;
    float* scale = (float*)(al + A_ELEMS);
    float* bias  = scale + OC;

    prep_weights<<<A_ELEMS / 256, 256, 0, stream>>>(phase, gamma, beta, rmean, rvar,
                                                    ah, al, scale, bias);
    prep_x<<<dim3(HP, NB), 256, 0, stream>>>(x, xh, xl);
    conv_gemm<<<NB * 50, 256, 0, stream>>>(ah, al, xh, xl, scale, bias, out);
}